// Round 12
// baseline (1449.461 us; speedup 1.0000x reference)
//
#include <hip/hip_runtime.h>
#include <math.h>

#define S_MAX 64
#define D_MAX 128          // ws sizing
#define RING 128           // LDS ring depth (generic path, power of 2)
#define RMASK 127
#define D_SPEC 50          // specialized duration count (runtime-detected)
#define F_MAX 96
#define OBS_ROWS 16
#define EPSF 1e-8f
#define NEGF -1e30f

__device__ __forceinline__ float softplusf(float x) {
    return fmaxf(x, 0.0f) + log1pf(expf(-fabsf(x)));
}

// X-macro lists: 50 indices forward, and 49 shift pairs (reversed)
#define XL50(X) X(0) X(1) X(2) X(3) X(4) X(5) X(6) X(7) X(8) X(9) \
 X(10) X(11) X(12) X(13) X(14) X(15) X(16) X(17) X(18) X(19) \
 X(20) X(21) X(22) X(23) X(24) X(25) X(26) X(27) X(28) X(29) \
 X(30) X(31) X(32) X(33) X(34) X(35) X(36) X(37) X(38) X(39) \
 X(40) X(41) X(42) X(43) X(44) X(45) X(46) X(47) X(48) X(49)

#define XSHIFT(P) P(49,48) P(48,47) P(47,46) P(46,45) P(45,44) P(44,43) P(43,42) \
 P(42,41) P(41,40) P(40,39) P(39,38) P(38,37) P(37,36) P(36,35) P(35,34) \
 P(34,33) P(33,32) P(32,31) P(31,30) P(30,29) P(29,28) P(28,27) P(27,26) \
 P(26,25) P(25,24) P(24,23) P(23,22) P(22,21) P(21,20) P(20,19) P(19,18) \
 P(18,17) P(17,16) P(16,15) P(15,14) P(14,13) P(13,12) P(12,11) P(11,10) \
 P(10,9) P(9,8) P(8,7) P(7,6) P(6,5) P(5,4) P(4,3) P(3,2) P(2,1) P(1,0)

// ---------------- Kernel 1: params prep ------------------------------------
__global__ __launch_bounds__(256)
void prep_kernel(const float* __restrict__ logits,
                 const float* __restrict__ log_vars,
                 const float* __restrict__ shape_p,
                 const float* __restrict__ rate_p,
                 const int* __restrict__ max_d_p, const int* __restrict__ min_d_p,
                 float* __restrict__ dur_lp, float* __restrict__ trans,
                 float* __restrict__ ivar, float* __restrict__ svl,
                 int S, int F) {
    int tid = threadIdx.x;
    int min_d = *min_d_p, max_d = *max_d_p;
    int D = max_d - min_d + 1;
    if (D > RMASK) D = RMASK;   // must match viterbi clamp

    for (int s = tid; s < S; s += blockDim.x) {
        float acc = 0.f;
        for (int f = 0; f < F; ++f) {
            float lv = log_vars[s * F + f];
            ivar[s * F + f] = expf(-lv);
            acc += lv;
        }
        svl[s] = acc;
    }
    for (int s = tid; s < S; s += blockDim.x) {
        float a = softplusf(shape_p[s]);
        float r = softplusf(rate_p[s]);
        float lga = lgammaf(a);
        float alr = a * logf(r + EPSF);
        for (int di = 0; di < D; ++di) {
            float dval = (float)(min_d + di);
            float lp = (a - 1.f) * logf(dval + EPSF) - r * dval - lga + alr;
            dur_lp[s * D + di] = logf(expf(lp) + EPSF);
        }
    }
    for (int p = tid; p < S; p += blockDim.x) {
        float m = -INFINITY;
        for (int j = 0; j < S; ++j)
            if (j != p) m = fmaxf(m, logits[p * S + j]);
        float sum = 0.f;
        for (int j = 0; j < S; ++j)
            if (j != p) sum += expf(logits[p * S + j] - m);
        for (int j = 0; j < S; ++j) {
            float v;
            if (j == p) v = NEGF;
            else v = logf(expf(logits[p * S + j] - m) / sum + EPSF);
            trans[p * S + j] = v;
        }
    }
}

// ---------------- Kernel 2: observation log-probs ---------------------------
__global__ __launch_bounds__(256)
void obs_kernel(const float* __restrict__ obs,
                const float* __restrict__ means,
                const float* __restrict__ ivar,
                const float* __restrict__ svl,
                float* __restrict__ obs_lp,
                int BT, int S, int F) {
    __shared__ float sMean[S_MAX * (F_MAX + 1)];
    __shared__ float sIvar[S_MAX * (F_MAX + 1)];
    __shared__ float sObs[OBS_ROWS][F_MAX];

    int tid = threadIdx.x + threadIdx.y * 64;
    int PF = F + 1;
    for (int i = tid; i < S * F; i += 256) {
        int ss = i / F, ff = i % F;
        sMean[ss * PF + ff] = means[i];
        sIvar[ss * PF + ff] = ivar[i];
    }
    int row0 = blockIdx.x * OBS_ROWS;
    for (int i = tid; i < OBS_ROWS * F; i += 256) {
        int r = i / F, f = i % F;
        if (row0 + r < BT) sObs[r][f] = obs[(size_t)(row0 + r) * F + f];
    }
    __syncthreads();

    int s = threadIdx.x;
    if (s >= S) return;
    const float* mr = &sMean[s * PF];
    const float* vr = &sIvar[s * PF];
    const float LOG2PI = 1.8378770664093453f;
    float base = svl[s] + (float)F * LOG2PI;

    for (int r = threadIdx.y; r < OBS_ROWS; r += 4) {
        int row = row0 + r;
        if (row >= BT) break;
        float quad = 0.f;
        for (int f = 0; f < F; ++f) {
            float d = sObs[r][f] - mr[f];
            quad = fmaf(d * d, vr[f], quad);
        }
        obs_lp[(size_t)row * S + s] = -0.5f * (quad + base);
    }
}

__device__ __forceinline__ float lane_bcast(float v, int lane) {
    return __uint_as_float(__builtin_amdgcn_readlane(__float_as_uint(v), lane));
}

// ---------------- Kernel 3a: SPECIALIZED Viterbi (D==50, S==64) -------------
// One wave per batch; lane s owns state s. History rings are 150 NAMED
// SCALARS (m0..m49, c0..c49, d0..d49) -> pure SSA, no alloca, cannot go to
// scratch (the R9 array version stayed at VGPR=124 => compiler demoted the
// 50-element arrays to scratch; named scalars force register residency).
// Pre-init encodes M[-1]=0, M[<-1]=NEG, csum[<=0]=0 -> no edge selects.
__global__ __launch_bounds__(64, 1)   // 1 wave/EU: full VGPR budget
void viterbi_spec(const float* __restrict__ obs_lp,
                  const float* __restrict__ dur_g,
                  const float* __restrict__ trans_g,
                  int* __restrict__ bp_g, int* __restrict__ argd_g,
                  float* __restrict__ out,
                  const int* __restrict__ max_d_p, const int* __restrict__ min_d_p,
                  int B, int T, int S) {
    int D = *max_d_p - *min_d_p + 1;
    if (!(D == D_SPEC && S == 64)) return;   // viterbi_gen handles other shapes

    __shared__ float transL[64 * 64];        // 16 KB: trans[p][s], row-major
    int b = blockIdx.x;
    int s = threadIdx.x;                     // 0..63

    for (int i = s; i < 64 * 64; i += 64) transL[i] = trans_g[i];
    __syncthreads();                         // one-time; fences LDS writes

    // ---- named scalar state: m<i> = M[e-1-i][s], c<i> = csum[max(e-i,0)][s],
    //      d<i> = dur_lp[s][i]
#define DECL(i) float m##i, c##i, d##i;
    XL50(DECL)
#undef DECL
#define INIT(i) m##i = NEGF; c##i = 0.f; d##i = dur_g[s * D_SPEC + (i)];
    XL50(INIT)
#undef INIT
    m0 = 0.f;                                // M[-1] = 0 (start state)

    const float* obsb = obs_lp + (size_t)b * T * 64;
    int* bpb = bp_g + (size_t)b * T * 64;
    int* adb = argd_g + (size_t)b * T * 64;
    const float* tc = &transL[s];            // column s, stride 64 floats

    float csum = 0.f;
    float o_cur = (T > 0) ? obsb[s] : 0.f;
    float finV = -INFINITY; int finI = 0x7fffffff;

    for (int e = 0; e < T; ++e) {
        float o_nxt = (e + 1 < T) ? obsb[(size_t)(e + 1) * 64 + s] : 0.f;

        csum += o_cur;                       // csum[e+1] (sequential prefix sum)
        float ce1 = csum;

        // ---- duration argmax: v = (M[e-1-i] + (ce1 - csum[e-i])) + dur[i]
        // two chains (even/odd i); ((i)&1) constant-folds per macro instance
        float bv0 = -INFINITY, bv1 = -INFINITY;
        int bi0 = 0, bi1 = 1;
#define DUR(i) { float v = (m##i + (ce1 - c##i)) + d##i; \
        if (((i) & 1) == 0) { if (v > bv0) { bv0 = v; bi0 = (i); } } \
        else                { if (v > bv1) { bv1 = v; bi1 = (i); } } }
        XL50(DUR)
#undef DUR
        float A; int ad;
        if (bv1 > bv0 || (bv1 == bv0 && bi1 < bi0)) { A = bv1; ad = bi1; }
        else { A = bv0; ad = bi0; }

        if (e == T - 1) { finV = A; finI = s * D_SPEC + ad; }  // flat s-major
        adb[(size_t)e * 64 + s] = ad;

        // ---- transition: M[s] = max_p A[p] + trans[p][s]
        // A[p] via readlane (VALU), trans[p][s] via LDS imm-offset reads
        float M0 = -INFINITY, M1 = -INFINITY;
        int p0 = 0, p1 = 1;
#pragma unroll
        for (int p = 0; p < 64; p += 2) {
            float v0 = lane_bcast(A, p) + tc[p * 64];
            if (v0 > M0) { M0 = v0; p0 = p; }
            float v1 = lane_bcast(A, p + 1) + tc[(p + 1) * 64];
            if (v1 > M1) { M1 = v1; p1 = p + 1; }
        }
        float M; int bp;
        if (M1 > M0 || (M1 == M0 && p1 < p0)) { M = M1; bp = p1; }
        else { M = M0; bp = p0; }
        bpb[(size_t)e * 64 + s] = bp;

        // ---- shift the named-scalar rings (pure register moves)
#define SH(a, b) m##a = m##b; c##a = c##b;
        XSHIFT(SH)
#undef SH
        m0 = M;
        c0 = ce1;
        o_cur = o_nxt;
    }

    // ---- wave-wide final argmax (max value, min flat index on tie)
#pragma unroll
    for (int off = 32; off; off >>= 1) {
        float v2 = __shfl_xor(finV, off);
        int i2 = __shfl_xor(finI, off);
        if (v2 > finV || (v2 == finV && i2 < finI)) { finV = v2; finI = i2; }
    }

    if (s == 0) {
        float score = finV;
        int s0 = finI / D_SPEC;
        int d0 = finI % D_SPEC + 1;

        float* dec = out + (size_t)b * T;
        int t = T - 1, cs = s0, cd = d0;
        while (t >= 0) {
            int lo = t - cd + 1; if (lo < 0) lo = 0;
            for (int j = lo; j <= t; ++j) dec[j] = (float)cs;
            int tau = t - cd;
            int i = tau; if (i < 0) i = 0; if (i > T - 1) i = T - 1;
            int ps = bpb[(size_t)i * 64 + cs];
            int pd = adb[(size_t)i * 64 + ps] + 1;
            t = tau; cs = ps; cd = pd;
        }
        out[(size_t)B * T + b] = score;
    }
}

// ---------------- Kernel 3b: GENERIC Viterbi (any S<=64, D<=127) ------------
struct VLds {
    float Mring[RING][S_MAX];
    float cring[RING][S_MAX];
    float durL[RING][S_MAX];
    float transL[S_MAX * S_MAX];
};

__global__ __launch_bounds__(64)
void viterbi_gen(const float* __restrict__ obs_lp,
                 const float* __restrict__ dur_g,
                 const float* __restrict__ trans_g,
                 int* __restrict__ bp_g, int* __restrict__ argd_g,
                 float* __restrict__ out,
                 const int* __restrict__ max_d_p, const int* __restrict__ min_d_p,
                 int B, int T, int S) {
    int D = *max_d_p - *min_d_p + 1;
    if (D == D_SPEC && S == 64) return;      // viterbi_spec handled it
    if (D > RMASK) D = RMASK;

    __shared__ VLds L;
    int b = blockIdx.x;
    int s = threadIdx.x;

    for (int i = s; i < S * D; i += 64) {
        int ss = i / D, dd = i % D;
        L.durL[dd][ss] = dur_g[i];
    }
    for (int i = s; i < S * S; i += 64) L.transL[i] = trans_g[i];
    __syncthreads();

    const float* obsb = obs_lp + (size_t)b * T * S;
    int* bpb = bp_g + (size_t)b * T * S;
    int* adb = argd_g + (size_t)b * T * S;

    bool act = (s < S);
    if (act) L.cring[0][s] = 0.f;
    float csum = 0.f;
    float o_cur = (act && T > 0) ? obsb[s] : 0.f;
    float finV = -INFINITY; int finI = 0x7fffffff;

    for (int e = 0; e < T; ++e) {
        float o_nxt = 0.f;
        if (act && e + 1 < T) o_nxt = obsb[(size_t)(e + 1) * S + s];
        csum += o_cur;
        if (act) L.cring[(e + 1) & RMASK][s] = csum;
        float ce1 = csum;

        float bv = -INFINITY; int bi = 0;
#pragma unroll 4
        for (int di = 0; di < D; ++di) {
            int tau = e - 1 - di;
            float mr = L.Mring[tau & RMASK][s & 63];
            float mval = (tau == -1) ? 0.f : (tau < -1 ? NEGF : mr);
            int st = tau + 1;
            float cr = L.cring[st & RMASK][s & 63];
            float cb = (st <= 0) ? 0.f : cr;
            float v = mval + (ce1 - cb) + L.durL[di][s & 63];
            if (v > bv) { bv = v; bi = di; }
        }
        float A = act ? bv : NEGF;
        int ad = bi;
        if (act && e == T - 1) { finV = A; finI = s * D + ad; }
        if (act) adb[(size_t)e * S + s] = ad;

        float M = -INFINITY; int bp = 0;
        for (int p = 0; p < S; ++p) {
            float a = __shfl(A, p);
            float v = a + L.transL[p * S + (s < S ? s : 0)];
            if (v > M) { M = v; bp = p; }
        }
        if (act) {
            L.Mring[e & RMASK][s] = M;
            bpb[(size_t)e * S + s] = bp;
        }
        o_cur = o_nxt;
    }

#pragma unroll
    for (int off = 32; off; off >>= 1) {
        float v2 = __shfl_xor(finV, off);
        int i2 = __shfl_xor(finI, off);
        if (v2 > finV || (v2 == finV && i2 < finI)) { finV = v2; finI = i2; }
    }

    if (s == 0) {
        float score = finV;
        int s0 = finI / D;
        int d0 = finI % D + 1;

        float* dec = out + (size_t)b * T;
        int t = T - 1, cs = s0, cd = d0;
        while (t >= 0) {
            int lo = t - cd + 1; if (lo < 0) lo = 0;
            for (int j = lo; j <= t; ++j) dec[j] = (float)cs;
            int tau = t - cd;
            int i = tau; if (i < 0) i = 0; if (i > T - 1) i = T - 1;
            int ps = bpb[(size_t)i * S + cs];
            int pd = adb[(size_t)i * S + ps] + 1;
            t = tau; cs = ps; cd = pd;
        }
        out[(size_t)B * T + b] = score;
    }
}

// ---------------- Host launch ------------------------------------------------
extern "C" void kernel_launch(void* const* d_in, const int* in_sizes, int n_in,
                              void* d_out, int out_size, void* d_ws, size_t ws_size,
                              hipStream_t stream) {
    const float* obs     = (const float*)d_in[0];
    const float* logits  = (const float*)d_in[1];
    const float* means   = (const float*)d_in[2];
    const float* logvars = (const float*)d_in[3];
    const float* shp     = (const float*)d_in[4];
    const float* rate    = (const float*)d_in[5];
    const int*   maxd    = (const int*)d_in[6];
    const int*   mind    = (const int*)d_in[7];
    float* out = (float*)d_out;

    int S  = in_sizes[4];
    int F  = in_sizes[2] / S;
    int BT = in_sizes[0] / F;
    int B  = out_size - BT;      // out_size = B*T + B
    int T  = BT / B;

    float* ws    = (float*)d_ws;
    float* dur   = ws;                                // S * D_MAX
    float* trans = dur + (size_t)S * D_MAX;           // S * S
    float* ivar  = trans + (size_t)S * S;             // S * F
    float* svl   = ivar + (size_t)S * F;              // S
    float* obslp = svl + S;                           // BT * S
    int*   bp    = (int*)(obslp + (size_t)BT * S);    // BT * S
    int*   ad    = bp + (size_t)BT * S;               // BT * S

    prep_kernel<<<1, 256, 0, stream>>>(logits, logvars, shp, rate, maxd, mind,
                                       dur, trans, ivar, svl, S, F);
    obs_kernel<<<(BT + OBS_ROWS - 1) / OBS_ROWS, dim3(64, 4), 0, stream>>>(
        obs, means, ivar, svl, obslp, BT, S, F);
    // Both launched every call (graph-capture-safe); device-side shape guards
    // make exactly one do the work.
    viterbi_spec<<<B, 64, 0, stream>>>(obslp, dur, trans, bp, ad, out,
                                       maxd, mind, B, T, S);
    viterbi_gen<<<B, 64, 0, stream>>>(obslp, dur, trans, bp, ad, out,
                                      maxd, mind, B, T, S);
}